// Round 11
// baseline (89.329 us; speedup 1.0000x reference)
//
#include <hip/hip_runtime.h>
#include <stdint.h>

#define BATCH 16384
#define NF 768
#define FT 1024
#define RBB 32              // batch rows per block
#define GR 64               // GEMM rows per block (stm 0-31, nstm 32-63)
#define THREADS 256
#define NKS 12              // 768 / 64 K-steps
#define ABLK (NKS * 4 * 64 * 16)   // 49152 B fragment-ordered A tile

typedef int i32x4 __attribute__((ext_vector_type(4)));

// ---- prep: W_ft [FT][NF] f32 -> Wq [FT][NF] i8 (per-row scale 127/absmax) --
__global__ __launch_bounds__(192) void prep_wq(const float* __restrict__ W_ft,
                                               char* __restrict__ Wq,
                                               float* __restrict__ invs) {
    const int o = blockIdx.x;
    const int t = threadIdx.x;
    __shared__ float smax[3];
    __shared__ float sscale;
    const float4 v = *(const float4*)(W_ft + (size_t)o * NF + t * 4);
    float m = fmaxf(fmaxf(fabsf(v.x), fabsf(v.y)), fmaxf(fabsf(v.z), fabsf(v.w)));
    #pragma unroll
    for (int s = 32; s > 0; s >>= 1) m = fmaxf(m, __shfl_down(m, s, 64));
    if ((t & 63) == 0) smax[t >> 6] = m;
    __syncthreads();
    if (t == 0) {
        const float am = fmaxf(fmaxf(smax[0], smax[1]), smax[2]);
        sscale = 127.0f / am;
        invs[o] = am / 127.0f;
    }
    __syncthreads();
    const float s = sscale;
    const float arr[4] = {v.x, v.y, v.z, v.w};
    uint32_t pk = 0;
    #pragma unroll
    for (int j = 0; j < 4; ++j) {
        const int q = (int)rintf(arr[j] * s);
        pk |= ((uint32_t)(unsigned char)(char)q) << (8 * j);
    }
    *(uint32_t*)(Wq + (size_t)o * NF + t * 4) = pk;
}

__device__ __forceinline__ uint32_t pack01(float4 v) {
    return (uint32_t)(v.x != 0.0f) | ((uint32_t)(v.y != 0.0f) << 8)
         | ((uint32_t)(v.z != 0.0f) << 16) | ((uint32_t)(v.w != 0.0f) << 24);
}

// ---- fused dense i8-MFMA FT + SCReLU + output layer + sigmoid --------------
// 256 threads / 4 waves; tile = 32 batch rows (64 GEMM rows) x 1024 cols done
// as 4 chunks of 256 cols (wave owns 64 cols/chunk, acc[4][4] reused, fused
// per-chunk epilogue into running ps). 49KB LDS -> 2-3 blocks/CU, one round.
__global__ __launch_bounds__(THREADS, 2) void nnue_mfma(
    const float* __restrict__ bstm, const float* __restrict__ bnstm,
    const char* __restrict__ Wq, const float* __restrict__ invs,
    const float* __restrict__ b_ft, const float* __restrict__ W_out,
    const float* __restrict__ b_out, float* __restrict__ out)
{
    __shared__ __align__(16) char Albs[ABLK];   // 48 KB
    __shared__ float red[GR][4];                // 1 KB

    const int t = threadIdx.x;
    const int w = t >> 6;
    const int l = t & 63;
    const int b0 = blockIdx.x * RBB;

    // Phase 1: stage 64 board rows -> i8 {0,1} fragment-order LDS.
    // 3072 16B-chunks (= 64B f32 each); 12 per thread; coalesced chunkid = i*256+t.
    #pragma unroll
    for (int bt = 0; bt < 3; ++bt) {
        float4 v[16];
        int rows[4], c16s[4];
        #pragma unroll
        for (int u = 0; u < 4; ++u) {
            const int chunkid = (bt * 4 + u) * THREADS + t;
            const int row = chunkid / 48;
            const int c16 = chunkid - row * 48;
            rows[u] = row; c16s[u] = c16;
            const float* src = ((row < RBB)
                ? (bstm + (size_t)(b0 + row) * NF)
                : (bnstm + (size_t)(b0 + row - RBB) * NF)) + c16 * 16;
            #pragma unroll
            for (int k = 0; k < 4; ++k)
                v[u * 4 + k] = *(const float4*)(src + k * 4);
        }
        __builtin_amdgcn_sched_barrier(0);   // keep all 16 loads in flight
        #pragma unroll
        for (int u = 0; u < 4; ++u) {
            const int row = rows[u], c16 = c16s[u];
            const int r = row >> 4, cl2 = row & 15;
            const int ks = c16 >> 2, qq = c16 & 3;
            uint4 o;
            o.x = pack01(v[u * 4 + 0]); o.y = pack01(v[u * 4 + 1]);
            o.z = pack01(v[u * 4 + 2]); o.w = pack01(v[u * 4 + 3]);
            const int slot = ((ks * 4 + r) << 6) + (qq << 4) + cl2;
            *(uint4*)(&Albs[(size_t)slot << 4]) = o;
        }
    }
    __syncthreads();

    // Phase 2: chunk loop over col ranges; K-loop with depth-1 B prefetch.
    const int cl = l & 15;
    const int q = l >> 4;
    const i32x4* af = (const i32x4*)Albs;   // af[(ks*4+r)*64 + l]
    float ps[4][4] = {};                    // running per-row partials

    #pragma unroll
    for (int ch = 0; ch < 4; ++ch) {
        const int colbase = ch * 256 + w * 64;
        const char* bp = Wq + (size_t)(colbase + cl) * NF + q * 16;

        i32x4 bcur[4];
        #pragma unroll
        for (int c = 0; c < 4; ++c)
            bcur[c] = *(const i32x4*)(bp + (size_t)c * 16 * NF);

        // chunk epilogue params (issued early, ready by epilogue)
        float iv[4], bf[4], wos[4], won[4];
        #pragma unroll
        for (int c = 0; c < 4; ++c) {
            const int col = colbase + c * 16 + cl;
            iv[c] = invs[col]; bf[c] = b_ft[col];
            wos[c] = W_out[col]; won[c] = W_out[FT + col];
        }

        i32x4 acc[4][4];
        #pragma unroll
        for (int r = 0; r < 4; ++r)
            #pragma unroll
            for (int c = 0; c < 4; ++c)
                acc[r][c] = (i32x4){0, 0, 0, 0};

        #pragma unroll
        for (int ks = 0; ks < NKS; ++ks) {
            i32x4 bnxt[4];
            if (ks < NKS - 1) {
                #pragma unroll
                for (int c = 0; c < 4; ++c)
                    bnxt[c] = *(const i32x4*)(bp + (size_t)c * 16 * NF + (ks + 1) * 64);
            }
            __builtin_amdgcn_s_setprio(1);
            #pragma unroll
            for (int r = 0; r < 4; ++r) {
                const i32x4 a = af[(ks * 4 + r) * 64 + l];
                #pragma unroll
                for (int c = 0; c < 4; ++c)
                    acc[r][c] = __builtin_amdgcn_mfma_i32_16x16x64_i8(
                        a, bcur[c], acc[r][c], 0, 0, 0);
            }
            __builtin_amdgcn_s_setprio(0);
            #pragma unroll
            for (int c = 0; c < 4; ++c) bcur[c] = bnxt[c];
        }

        // fused chunk epilogue: dequant + bias + SCReLU + W_out dot -> ps
        #pragma unroll
        for (int c = 0; c < 4; ++c) {
            #pragma unroll
            for (int r = 0; r < 4; ++r) {
                const float wo = (r < 2) ? wos[c] : won[c];  // 0-31 stm, 32-63 nstm
                #pragma unroll
                for (int j = 0; j < 4; ++j) {
                    float h = fmaf((float)acc[r][c][j], iv[c], bf[c]);
                    h = fminf(fmaxf(h, 0.0f), 1.0f);
                    ps[r][j] = fmaf(h * h, wo, ps[r][j]);
                }
            }
        }
    }

    // Phase 3: reduce over the 16 col-lanes; cross-wave via LDS.
    #pragma unroll
    for (int r = 0; r < 4; ++r)
        #pragma unroll
        for (int j = 0; j < 4; ++j) {
            float v = ps[r][j];
            v += __shfl_xor(v, 1, 64);
            v += __shfl_xor(v, 2, 64);
            v += __shfl_xor(v, 4, 64);
            v += __shfl_xor(v, 8, 64);
            if (cl == 0) red[16 * r + 4 * q + j][w] = v;
        }
    __syncthreads();

    // Phase 4: per batch row, stm(t) + nstm(32+t) over 4 waves.
    if (t < RBB) {
        float x = b_out[0];
        #pragma unroll
        for (int w2 = 0; w2 < 4; ++w2)
            x += red[t][w2] + red[RBB + t][w2];
        out[b0 + t] = 1.0f / (1.0f + expf(-x));
    }
}

extern "C" void kernel_launch(void* const* d_in, const int* in_sizes, int n_in,
                              void* d_out, int out_size, void* d_ws, size_t ws_size,
                              hipStream_t stream) {
    const float* board_stm  = (const float*)d_in[0];
    const float* board_nstm = (const float*)d_in[1];
    const float* W_ft       = (const float*)d_in[2];
    const float* b_ft       = (const float*)d_in[3];
    const float* W_out      = (const float*)d_in[4];
    const float* b_out      = (const float*)d_in[5];
    float* out = (float*)d_out;

    char* Wq = (char*)d_ws;                                   // 768 KB
    float* invs = (float*)((char*)d_ws + (size_t)FT * NF);    // 4 KB

    prep_wq<<<FT, 192, 0, stream>>>(W_ft, Wq, invs);
    nnue_mfma<<<BATCH / RBB, THREADS, 0, stream>>>(
        board_stm, board_nstm, Wq, invs, b_ft, W_out, b_out, out);
}

// Round 12
// 75.701 us; speedup vs baseline: 1.1800x; 1.1800x over previous
//
#include <hip/hip_runtime.h>
#include <stdint.h>

#define BATCH 16384
#define NF 768
#define FT 1024
#define RBB 32              // batch rows per block
#define GR 64               // GEMM rows (stm 0-31, nstm 32-63)
#define THREADS 512
#define NKS 12              // 768/64 K-steps
#define NPH 24              // phases = K-steps x 2 col-halves
#define ABYTES (NKS * 4 * 64 * 16)   // 49152 frag-ordered A
#define BSLOT 4096                   // per (ring-slot, wave) B bytes
#define BBYTES (3 * 8 * BSLOT)       // 98304 ring-3 x 8 waves

typedef int i32x4 __attribute__((ext_vector_type(4)));

// ---- prep: W_ft [FT][NF] f32 -> Wq [FT][NF] i8 (per-row scale 127/absmax) --
__global__ __launch_bounds__(192) void prep_wq(const float* __restrict__ W_ft,
                                               char* __restrict__ Wq,
                                               float* __restrict__ invs) {
    const int o = blockIdx.x;
    const int t = threadIdx.x;
    __shared__ float smax[3];
    __shared__ float sscale;
    const float4 v = *(const float4*)(W_ft + (size_t)o * NF + t * 4);
    float m = fmaxf(fmaxf(fabsf(v.x), fabsf(v.y)), fmaxf(fabsf(v.z), fabsf(v.w)));
    #pragma unroll
    for (int s = 32; s > 0; s >>= 1) m = fmaxf(m, __shfl_down(m, s, 64));
    if ((t & 63) == 0) smax[t >> 6] = m;
    __syncthreads();
    if (t == 0) {
        const float am = fmaxf(fmaxf(smax[0], smax[1]), smax[2]);
        sscale = 127.0f / am;
        invs[o] = am / 127.0f;
    }
    __syncthreads();
    const float s = sscale;
    const float arr[4] = {v.x, v.y, v.z, v.w};
    uint32_t pk = 0;
    #pragma unroll
    for (int j = 0; j < 4; ++j) {
        const int q = (int)rintf(arr[j] * s);
        pk |= ((uint32_t)(unsigned char)(char)q) << (8 * j);
    }
    *(uint32_t*)(Wq + (size_t)o * NF + t * 4) = pk;
}

__device__ __forceinline__ uint32_t pack01(float4 v) {
    return (uint32_t)(v.x != 0.0f) | ((uint32_t)(v.y != 0.0f) << 8)
         | ((uint32_t)(v.z != 0.0f) << 16) | ((uint32_t)(v.w != 0.0f) << 24);
}

__device__ __forceinline__ void gload16(const void* g, void* l) {
    __builtin_amdgcn_global_load_lds(
        (const __attribute__((address_space(1))) unsigned int*)g,
        (__attribute__((address_space(3))) unsigned int*)l, 16, 0, 0);
}

// ---- fused dense i8-MFMA FT + SCReLU + output layer + sigmoid --------------
// 8 waves; wave w owns cols {w*64..+64} in each 512-col half -> acc[4][8].
// A: frag-order LDS (conflict-free). B: per-wave 4KB LDS ring slots filled by
// async global_load_lds, counted vmcnt(8), zero barriers in the K-loop.
__global__ __launch_bounds__(THREADS, 2) void nnue_mfma(
    const float* __restrict__ bstm, const float* __restrict__ bnstm,
    const char* __restrict__ Wq, const float* __restrict__ invs,
    const float* __restrict__ b_ft, const float* __restrict__ W_out,
    const float* __restrict__ b_out, float* __restrict__ out)
{
    __shared__ __align__(16) char Albs[ABYTES];   // 48 KB
    __shared__ __align__(16) char Bbs[BBYTES];    // 96 KB
    __shared__ float red[GR][8];                  // 2 KB

    const int t = threadIdx.x;
    const int w = t >> 6;
    const int l = t & 63;
    const int cl = l & 15;
    const int q = l >> 4;
    const int b0 = blockIdx.x * RBB;

    // ---- Phase A: stage 64 board rows f32 -> i8 {0,1} frag-order LDS ------
    // 3072 16B-chunks, 6/thread, 2 batches of 3 (12 float4 in flight each).
    #pragma unroll
    for (int bt = 0; bt < 2; ++bt) {
        float4 v[12];
        int row[3], c16[3];
        #pragma unroll
        for (int j = 0; j < 3; ++j) {
            const int id = (bt * 3 + j) * THREADS + t;
            row[j] = id / 48; c16[j] = id - row[j] * 48;
            const float* src = ((row[j] < RBB)
                ? (bstm + (size_t)(b0 + row[j]) * NF)
                : (bnstm + (size_t)(b0 + row[j] - RBB) * NF)) + c16[j] * 16;
            #pragma unroll
            for (int k = 0; k < 4; ++k)
                v[j * 4 + k] = *(const float4*)(src + k * 4);
        }
        __builtin_amdgcn_sched_barrier(0);   // keep the 12 loads in flight
        #pragma unroll
        for (int j = 0; j < 3; ++j) {
            uint4 o;
            o.x = pack01(v[j * 4 + 0]); o.y = pack01(v[j * 4 + 1]);
            o.z = pack01(v[j * 4 + 2]); o.w = pack01(v[j * 4 + 3]);
            const int ks = c16[j] >> 2, qq = c16[j] & 3;
            const int rr = row[j] >> 4, c2 = row[j] & 15;
            const int slotA = ((ks * 4 + rr) << 6) + (qq << 4) + c2;
            *(uint4*)(&Albs[(size_t)slotA << 4]) = o;
        }
    }

    // ---- B ring stage helper: phase p -> slot p%3, this wave's 64 cols ----
    const int srcLaneOff = cl * NF + q * 16;
    auto issueB = [&](int p) {
        const int slot = p % 3;
        const int ks = p >> 1;
        const int colbase = (p & 1) * 512 + w * 64;
        #pragma unroll
        for (int c = 0; c < 4; ++c)
            gload16(Wq + (size_t)(colbase + c * 16) * NF + ks * 64 + srcLaneOff,
                    Bbs + ((slot * 8 + w) * 4 + c) * 1024);
    };
    issueB(0); issueB(1); issueB(2);   // prologue (drained by the barrier)
    __syncthreads();

    // ---- K-loop: 24 phases, barrier-free -----------------------------------
    const i32x4* af = (const i32x4*)Albs;
    i32x4 acc[4][8] = {};
    i32x4 a[4];
    #pragma unroll
    for (int p = 0; p < NPH; ++p) {
        const int slot = p % 3;
        const int h = p & 1;
        const int ks = p >> 1;
        // wait for phase p's B writes (<=2 later phases may stay in flight)
        if (p < NPH - 2)       asm volatile("s_waitcnt vmcnt(8)" ::: "memory");
        else if (p == NPH - 2) asm volatile("s_waitcnt vmcnt(4)" ::: "memory");
        else                   asm volatile("s_waitcnt vmcnt(0)" ::: "memory");
        i32x4 b[4];
        #pragma unroll
        for (int c = 0; c < 4; ++c)
            b[c] = *(const i32x4*)(Bbs + ((slot * 8 + w) * 4 + c) * 1024 + l * 16);
        if (h == 0) {
            #pragma unroll
            for (int r = 0; r < 4; ++r)
                a[r] = af[(ks * 4 + r) * 64 + l];
        }
        // ds_reads must be complete before re-filling this ring slot
        asm volatile("s_waitcnt lgkmcnt(0)" ::: "memory");
        if (p + 3 < NPH) issueB(p + 3);
        __builtin_amdgcn_s_setprio(1);
        #pragma unroll
        for (int r = 0; r < 4; ++r)
            #pragma unroll
            for (int c = 0; c < 4; ++c)
                acc[r][h * 4 + c] = __builtin_amdgcn_mfma_i32_16x16x64_i8(
                    a[r], b[c], acc[r][h * 4 + c], 0, 0, 0);
        __builtin_amdgcn_s_setprio(0);
    }

    // ---- epilogue: dequant + bias + SCReLU + W_out dot ---------------------
    // C/D lane mapping: col=l&15, row=(l>>4)*4+j (validated r5-r11).
    float ps[4][4] = {};
    #pragma unroll
    for (int cc = 0; cc < 8; ++cc) {
        const int col = (cc >> 2) * 512 + w * 64 + (cc & 3) * 16 + cl;
        const float iv = invs[col];
        const float bf = b_ft[col];
        const float wo0 = W_out[col];
        const float wo1 = W_out[FT + col];
        #pragma unroll
        for (int r = 0; r < 4; ++r) {
            const float wo = (r < 2) ? wo0 : wo1;   // 0-31 stm, 32-63 nstm
            #pragma unroll
            for (int j = 0; j < 4; ++j) {
                float hh = fmaf((float)acc[r][cc][j], iv, bf);
                hh = fminf(fmaxf(hh, 0.0f), 1.0f);
                ps[r][j] = fmaf(hh * hh, wo, ps[r][j]);
            }
        }
    }
    #pragma unroll
    for (int r = 0; r < 4; ++r)
        #pragma unroll
        for (int j = 0; j < 4; ++j) {
            float v = ps[r][j];
            v += __shfl_xor(v, 1, 64);
            v += __shfl_xor(v, 2, 64);
            v += __shfl_xor(v, 4, 64);
            v += __shfl_xor(v, 8, 64);
            if (cl == 0) red[16 * r + 4 * q + j][w] = v;
        }
    __syncthreads();

    if (t < RBB) {
        float x = b_out[0];
        #pragma unroll
        for (int w2 = 0; w2 < 8; ++w2)
            x += red[t][w2] + red[RBB + t][w2];
        out[b0 + t] = 1.0f / (1.0f + expf(-x));
    }
}

extern "C" void kernel_launch(void* const* d_in, const int* in_sizes, int n_in,
                              void* d_out, int out_size, void* d_ws, size_t ws_size,
                              hipStream_t stream) {
    const float* board_stm  = (const float*)d_in[0];
    const float* board_nstm = (const float*)d_in[1];
    const float* W_ft       = (const float*)d_in[2];
    const float* b_ft       = (const float*)d_in[3];
    const float* W_out      = (const float*)d_in[4];
    const float* b_out      = (const float*)d_in[5];
    float* out = (float*)d_out;

    char* Wq = (char*)d_ws;                                   // 768 KB
    float* invs = (float*)((char*)d_ws + (size_t)FT * NF);    // 4 KB

    prep_wq<<<FT, 192, 0, stream>>>(W_ft, Wq, invs);
    nnue_mfma<<<BATCH / RBB, THREADS, 0, stream>>>(
        board_stm, board_nstm, Wq, invs, b_ft, W_out, b_out, out);
}